// Round 8
// baseline (215.051 us; speedup 1.0000x reference)
//
#include <hip/hip_runtime.h>

#define W_    1024
#define H_    1024
#define NIMG  16
#define HS    16             // output rows per block strip
#define NTHR  256            // 4 waves per block
#define PAD   4              // 9//2
#define EPS_  1e-5f
#define LDSW  1032           // padded columns: idx = col + 4; zeros at [0,4) and [1028,1032)

__device__ __forceinline__ float4 ldq(const float* p) {
    return *reinterpret_cast<const float4*>(p);
}
__device__ __forceinline__ float4 ldq_or0(const float* p, bool v) {
    return v ? *reinterpret_cast<const float4*>(p) : make_float4(0.f, 0.f, 0.f, 0.f);
}

__global__ __launch_bounds__(NTHR, 4) void ncc_main(const float* __restrict__ Iall,
                                                    const float* __restrict__ Jall,
                                                    float* __restrict__ acc)
{
    // XCD-chunked swizzle: 1024 blocks, 8 XCDs -> 128 consecutive strips per XCD
    const int bx    = blockIdx.x;
    const int sbx   = (bx & 7) * 128 + (bx >> 3);
    const int img   = sbx >> 6;          // 64 strips per image
    const int strip = sbx & 63;
    const int r0    = strip * HS;
    const int t     = threadIdx.x;
    const int c0    = t * 4;             // 4 contiguous cols per thread

    const float* __restrict__ Ib = Iall + (size_t)img * (W_ * H_) + c0;
    const float* __restrict__ Jb = Jall + (size_t)img * (W_ * H_) + c0;

    __shared__ float vs[5][LDSW];

    // zero pad borders (written once; in-loop writes cover idx [4,1028) only)
    if (t < 8) {
        const int idx = (t < 4) ? t : (1024 + t);
        #pragma unroll
        for (int ch = 0; ch < 5; ++ch) vs[ch][idx] = 0.0f;
    }

    // vertical running sums over rows [r-4, r+4] for 4 cols, 5 channels
    float vsum[5][4];
    #pragma unroll
    for (int ch = 0; ch < 5; ++ch)
        #pragma unroll
        for (int k = 0; k < 4; ++k) vsum[ch][k] = 0.f;

    // warm-up: rows r0-4 .. r0+3
    for (int q = r0 - PAD; q < r0 + PAD; ++q) {
        if (q >= 0) {
            const float4 a = ldq(Ib + (size_t)q * W_);
            const float4 b = ldq(Jb + (size_t)q * W_);
            const float av[4] = {a.x, a.y, a.z, a.w};
            const float bv[4] = {b.x, b.y, b.z, b.w};
            #pragma unroll
            for (int k = 0; k < 4; ++k) {
                vsum[0][k] += av[k];
                vsum[1][k] += bv[k];
                vsum[2][k] = __builtin_fmaf(av[k], av[k], vsum[2][k]);
                vsum[3][k] = __builtin_fmaf(bv[k], bv[k], vsum[3][k]);
                vsum[4][k] = __builtin_fmaf(av[k], bv[k], vsum[4][k]);
            }
        }
    }

    // prefetch first iteration's enter (r0+4) and leave (r0-4) rows
    float4 eI = ldq_or0(Ib + (size_t)(r0 + PAD) * W_, r0 + PAD < H_);
    float4 eJ = ldq_or0(Jb + (size_t)(r0 + PAD) * W_, r0 + PAD < H_);
    float4 lI = ldq_or0(Ib + (size_t)(r0 - PAD) * W_, r0 - PAD >= 0);
    float4 lJ = ldq_or0(Jb + (size_t)(r0 - PAD) * W_, r0 - PAD >= 0);

    float accum = 0.0f;
    const float inv81 = 1.0f / 81.0f;

    for (int r = r0; r < r0 + HS; ++r) {
        // add enter row r+4 (prefetched; zeros if out of range)
        {
            const float av[4] = {eI.x, eI.y, eI.z, eI.w};
            const float bv[4] = {eJ.x, eJ.y, eJ.z, eJ.w};
            #pragma unroll
            for (int k = 0; k < 4; ++k) {
                vsum[0][k] += av[k];
                vsum[1][k] += bv[k];
                vsum[2][k] = __builtin_fmaf(av[k], av[k], vsum[2][k]);
                vsum[3][k] = __builtin_fmaf(bv[k], bv[k], vsum[3][k]);
                vsum[4][k] = __builtin_fmaf(av[k], bv[k], vsum[4][k]);
            }
        }
        // publish vertical sums: 1x ds_write_b128 per channel (linear, bank-optimal)
        #pragma unroll
        for (int ch = 0; ch < 5; ++ch)
            *reinterpret_cast<float4*>(&vs[ch][c0 + 4]) =
                make_float4(vsum[ch][0], vsum[ch][1], vsum[ch][2], vsum[ch][3]);
        __syncthreads();

        // halo reads only: left quad (cols c0-4..c0-1) and right quad (c0+4..c0+7)
        float4 L[5], R[5];
        #pragma unroll
        for (int ch = 0; ch < 5; ++ch) {
            L[ch] = ldq(&vs[ch][c0]);
            R[ch] = ldq(&vs[ch][c0 + 8]);
        }

        // software-pipeline next iteration's enter (r+5) / leave (r-3) rows:
        // issue now, consume next iter — latency hides under horizontal compute
        const float4 eI2 = ldq_or0(Ib + (size_t)(r + PAD + 1) * W_, r + PAD + 1 < H_);
        const float4 eJ2 = ldq_or0(Jb + (size_t)(r + PAD + 1) * W_, r + PAD + 1 < H_);
        const float4 lI2 = ldq_or0(Ib + (size_t)(r - PAD + 1) * W_, r - PAD + 1 >= 0);
        const float4 lJ2 = ldq_or0(Jb + (size_t)(r - PAD + 1) * W_, r - PAD + 1 >= 0);

        // horizontal 9-window sliding sums; middle quad comes from registers
        float h[5][4];
        #pragma unroll
        for (int ch = 0; ch < 5; ++ch) {
            float w[12];
            w[0] = L[ch].x; w[1] = L[ch].y; w[2]  = L[ch].z; w[3]  = L[ch].w;
            w[4] = vsum[ch][0]; w[5] = vsum[ch][1]; w[6] = vsum[ch][2]; w[7] = vsum[ch][3];
            w[8] = R[ch].x; w[9] = R[ch].y; w[10] = R[ch].z; w[11] = R[ch].w;
            float s = w[0];
            #pragma unroll
            for (int x = 1; x < 9; ++x) s += w[x];
            h[ch][0] = s;
            #pragma unroll
            for (int c = 1; c < 4; ++c) { s += w[c + 8] - w[c - 1]; h[ch][c] = s; }
        }
        #pragma unroll
        for (int c = 0; c < 4; ++c) {
            const float SI = h[0][c], SJ = h[1][c];
            const float SII = h[2][c], SJJ = h[3][c], SIJ = h[4][c];
            const float cross = __builtin_fmaf(-SI * SJ, inv81, SIJ);
            const float iv    = __builtin_fmaf(-SI * SI, inv81, SII);
            const float jv    = __builtin_fmaf(-SJ * SJ, inv81, SJJ);
            accum = __builtin_fmaf(cross * cross,
                                   __builtin_amdgcn_rcpf(__builtin_fmaf(iv, jv, EPS_)),
                                   accum);
        }

        // subtract leave row r-4 (prefetched; zeros if out of range)
        {
            const float av[4] = {lI.x, lI.y, lI.z, lI.w};
            const float bv[4] = {lJ.x, lJ.y, lJ.z, lJ.w};
            #pragma unroll
            for (int k = 0; k < 4; ++k) {
                vsum[0][k] -= av[k];
                vsum[1][k] -= bv[k];
                vsum[2][k] = __builtin_fmaf(-av[k], av[k], vsum[2][k]);
                vsum[3][k] = __builtin_fmaf(-bv[k], bv[k], vsum[3][k]);
                vsum[4][k] = __builtin_fmaf(-av[k], bv[k], vsum[4][k]);
            }
        }
        __syncthreads();

        eI = eI2; eJ = eJ2; lI = lI2; lJ = lJ2;
    }

    // block reduction: wave shuffle + one atomic per wave
    #pragma unroll
    for (int off = 32; off > 0; off >>= 1) accum += __shfl_down(accum, off);
    if ((t & 63) == 0) atomicAdd(acc, accum);
}

__global__ void ncc_finalize(const float* __restrict__ acc, float* __restrict__ out)
{
    out[0] = 1.0f - acc[0] * (1.0f / (float)((size_t)NIMG * W_ * H_));
}

extern "C" void kernel_launch(void* const* d_in, const int* in_sizes, int n_in,
                              void* d_out, int out_size, void* d_ws, size_t ws_size,
                              hipStream_t stream)
{
    const float* I = (const float*)d_in[0];
    const float* J = (const float*)d_in[1];
    float* acc = (float*)d_ws;

    hipMemsetAsync(acc, 0, sizeof(float), stream);
    ncc_main<<<NIMG * (H_ / HS), NTHR, 0, stream>>>(I, J, acc);
    ncc_finalize<<<1, 1, 0, stream>>>(acc, (float*)d_out);
}

// Round 9
// 213.171 us; speedup vs baseline: 1.0088x; 1.0088x over previous
//
#include <hip/hip_runtime.h>

#define W_     1024
#define H_     1024
#define NIMG   16
#define HS     16
#define PAD    4
#define EPS_   1e-5f
#define TILEC  256
#define NTILE  (W_ / TILEC)             // 4
#define NSTRIP (H_ / HS)                // 64
#define NBLK   (NIMG * NSTRIP * NTILE)  // 4096

__device__ __forceinline__ float4 ldq(const float* p) {
    return *reinterpret_cast<const float4*>(p);
}
__device__ __forceinline__ float4 ldq_or0(const float* p, bool v) {
    return v ? *reinterpret_cast<const float4*>(p) : make_float4(0.f, 0.f, 0.f, 0.f);
}

__device__ __forceinline__ void updA(float (&s)[5][4], const float4& a, const float4& b) {
    const float av[4] = {a.x, a.y, a.z, a.w};
    const float bv[4] = {b.x, b.y, b.z, b.w};
    #pragma unroll
    for (int k = 0; k < 4; ++k) {
        s[0][k] += av[k];
        s[1][k] += bv[k];
        s[2][k] = __builtin_fmaf(av[k], av[k], s[2][k]);
        s[3][k] = __builtin_fmaf(bv[k], bv[k], s[3][k]);
        s[4][k] = __builtin_fmaf(av[k], bv[k], s[4][k]);
    }
}
__device__ __forceinline__ void updS(float (&s)[5][4], const float4& a, const float4& b) {
    const float av[4] = {a.x, a.y, a.z, a.w};
    const float bv[4] = {b.x, b.y, b.z, b.w};
    #pragma unroll
    for (int k = 0; k < 4; ++k) {
        s[0][k] -= av[k];
        s[1][k] -= bv[k];
        s[2][k] = __builtin_fmaf(-av[k], av[k], s[2][k]);
        s[3][k] = __builtin_fmaf(-bv[k], bv[k], s[3][k]);
        s[4][k] = __builtin_fmaf(-av[k], bv[k], s[4][k]);
    }
}

// One wave (64 threads) per block. Tile = 256 output cols x 16 rows.
// Vertical 9-row box sums ride in registers (running add/sub).
// Horizontal halo exchanged through wave-private LDS with NO barriers:
// intra-wave LDS RAW is ordered by the in-order per-wave LDS pipe +
// compiler-inserted lgkmcnt waits (wave-synchronous pattern).
__global__ __launch_bounds__(64) void ncc_main(const float* __restrict__ Iall,
                                               const float* __restrict__ Jall,
                                               float* __restrict__ acc)
{
    // bijective XCD-chunk swizzle: 8 XCDs x 512 consecutive tiles (2 images/XCD)
    const int bx  = blockIdx.x;
    const int sbx = (bx & 7) * (NBLK / 8) + (bx >> 3);
    const int tile  = sbx & (NTILE - 1);
    const int strip = (sbx >> 2) & (NSTRIP - 1);
    const int img   = sbx >> 8;            // NTILE*NSTRIP = 256

    const int r0 = strip * HS;
    const int C0 = tile * TILEC;
    const int l  = threadIdx.x;            // 0..63
    const int c0 = C0 + 4 * l;             // own quad base col

    const float* __restrict__ Ib = Iall + (size_t)img * (W_ * H_);
    const float* __restrict__ Jb = Jall + (size_t)img * (W_ * H_);

    // slots: [0..3]=halo-left, [4..259]=own 256 cols, [260..263]=halo-right
    __shared__ float vs[5][272];

    const bool eL   = (l == 0);
    const bool eR   = (l == 63);
    const bool edge = eL || eR;
    const bool hOwn = (eL && C0 > 0) || (eR && (C0 + TILEC) < W_);
    const int  hc   = eL ? (C0 - 4) : (C0 + TILEC);   // halo quad base col

    float vsum[5][4]  = {};
    float vsumH[5][4] = {};

    // warm-up rows r0-4 .. r0+3 (zeros above image = conv zero-pad)
    for (int q = r0 - PAD; q < r0 + PAD; ++q) {
        if (q >= 0) {
            const size_t ro = (size_t)q * W_;
            updA(vsum, ldq(Ib + ro + c0), ldq(Jb + ro + c0));
            const float4 ah = ldq_or0(Ib + ro + hc, hOwn);
            const float4 bh = ldq_or0(Jb + ro + hc, hOwn);
            if (edge) updA(vsumH, ah, bh);
        }
    }

    float accum = 0.0f;
    const float inv81 = 1.0f / 81.0f;

    for (int r = r0; r < r0 + HS; ++r) {
        const int  qe  = r + PAD, ql = r - PAD;
        const bool okE = qe < H_, okL = ql >= 0;
        const size_t roE = (size_t)qe * W_, roL = (size_t)ql * W_;

        // issue all global loads up front; leave-loads drain late (no barrier drain)
        const float4 eI  = ldq_or0(Ib + roE + c0, okE);
        const float4 eJ  = ldq_or0(Jb + roE + c0, okE);
        const float4 lI  = ldq_or0(Ib + roL + c0, okL);
        const float4 lJ  = ldq_or0(Jb + roL + c0, okL);
        const float4 eIh = ldq_or0(Ib + roE + hc, hOwn && okE);
        const float4 eJh = ldq_or0(Jb + roE + hc, hOwn && okE);
        const float4 lIh = ldq_or0(Ib + roL + hc, hOwn && okL);
        const float4 lJh = ldq_or0(Jb + roL + hc, hOwn && okL);

        // enter row r+4 -> vsum covers [r-4, r+4]
        updA(vsum, eI, eJ);
        #pragma unroll
        for (int ch = 0; ch < 5; ++ch)
            *reinterpret_cast<float4*>(&vs[ch][4 + 4 * l]) =
                make_float4(vsum[ch][0], vsum[ch][1], vsum[ch][2], vsum[ch][3]);
        if (edge) {
            updA(vsumH, eIh, eJh);
            const int hidx = eL ? 0 : 260;
            #pragma unroll
            for (int ch = 0; ch < 5; ++ch)
                *reinterpret_cast<float4*>(&vs[ch][hidx]) =
                    make_float4(vsumH[ch][0], vsumH[ch][1], vsumH[ch][2], vsumH[ch][3]);
        }

        // horizontal 9-window: L/R quads from LDS (lgkmcnt-ordered), middle in regs
        float h[5][4];
        #pragma unroll
        for (int ch = 0; ch < 5; ++ch) {
            const float4 Lq = ldq(&vs[ch][4 * l]);
            const float4 Rq = ldq(&vs[ch][4 * l + 8]);
            const float w[12] = {Lq.x, Lq.y, Lq.z, Lq.w,
                                 vsum[ch][0], vsum[ch][1], vsum[ch][2], vsum[ch][3],
                                 Rq.x, Rq.y, Rq.z, Rq.w};
            float s = w[0];
            #pragma unroll
            for (int x = 1; x < 9; ++x) s += w[x];
            h[ch][0] = s;
            #pragma unroll
            for (int c = 1; c < 4; ++c) { s += w[c + 8] - w[c - 1]; h[ch][c] = s; }
        }
        #pragma unroll
        for (int c = 0; c < 4; ++c) {
            const float SI = h[0][c], SJ = h[1][c];
            const float SII = h[2][c], SJJ = h[3][c], SIJ = h[4][c];
            const float cross = __builtin_fmaf(-SI * SJ, inv81, SIJ);
            const float iv    = __builtin_fmaf(-SI * SI, inv81, SII);
            const float jv    = __builtin_fmaf(-SJ * SJ, inv81, SJJ);
            accum = __builtin_fmaf(cross * cross,
                                   __builtin_amdgcn_rcpf(__builtin_fmaf(iv, jv, EPS_)),
                                   accum);
        }

        // leave row r-4 -> vsum covers [r-3, r+4] for next iteration
        updS(vsum, lI, lJ);
        if (edge) updS(vsumH, lIh, lJh);
    }

    #pragma unroll
    for (int off = 32; off > 0; off >>= 1) accum += __shfl_down(accum, off);
    if (l == 0) atomicAdd(acc, accum);
}

__global__ void ncc_finalize(const float* __restrict__ acc, float* __restrict__ out)
{
    out[0] = 1.0f - acc[0] * (1.0f / (float)((size_t)NIMG * W_ * H_));
}

extern "C" void kernel_launch(void* const* d_in, const int* in_sizes, int n_in,
                              void* d_out, int out_size, void* d_ws, size_t ws_size,
                              hipStream_t stream)
{
    const float* I = (const float*)d_in[0];
    const float* J = (const float*)d_in[1];
    float* acc = (float*)d_ws;

    hipMemsetAsync(acc, 0, sizeof(float), stream);
    ncc_main<<<NBLK, 64, 0, stream>>>(I, J, acc);
    ncc_finalize<<<1, 1, 0, stream>>>(acc, (float*)d_out);
}